// Round 2
// baseline (20649.539 us; speedup 1.0000x reference)
//
#include <hip/hip_runtime.h>
#include <hip/hip_bf16.h>
#include <math.h>

#define V 65
#define D 384
#define NL 12
#define T 512
#define B 32
#define DI 768
#define DS 16
#define DC 4
#define DTR 24
#define DFF 1536
#define EPS 1e-5f
#define M_ROWS (B*T)   // 16384

// ---------------- embedding ----------------
__global__ __launch_bounds__(256) void embed_kernel(
    const int* __restrict__ idx, const float* __restrict__ tok,
    const float* __restrict__ pos, float* __restrict__ x) {
  int i = blockIdx.x * 256 + threadIdx.x;      // over M_ROWS*D
  int row = i / D, d = i - row * D;
  int t = row % T;
  x[i] = tok[idx[row] * D + d] + pos[t * D + d];
}

// ---------------- layernorm (1 wave per row of D=384) ----------------
__global__ __launch_bounds__(256) void ln_kernel(
    const float* __restrict__ in, const float* __restrict__ g,
    const float* __restrict__ b, float* __restrict__ out) {
  int wave = threadIdx.x >> 6;
  int lane = threadIdx.x & 63;
  int row = blockIdx.x * 4 + wave;
  const float* p = in + (size_t)row * D;
  float v[6];
  float s = 0.f, ss = 0.f;
#pragma unroll
  for (int i = 0; i < 6; i++) {
    v[i] = p[lane + i * 64];
    s += v[i];
    ss += v[i] * v[i];
  }
#pragma unroll
  for (int o = 1; o < 64; o <<= 1) {
    s += __shfl_xor(s, o, 64);
    ss += __shfl_xor(ss, o, 64);
  }
  float mu = s * (1.f / D);
  float var = ss * (1.f / D) - mu * mu;
  float rs = rsqrtf(var + EPS);
  float* q = out + (size_t)row * D;
#pragma unroll
  for (int i = 0; i < 6; i++) {
    int d = lane + i * 64;
    q[d] = (v[i] - mu) * rs * g[d] + b[d];
  }
}

// ---------------- generic fp32 GEMM: C[M,N] = A[M,K] @ Bw[N,K]^T ----------------
// ACT: 0 none, 1 relu, 2 softplus. Epilogue order: bias -> act -> +res.
template <int BM, int BN, int BK, int TM, int TN, int ACT, bool BIAS, bool RES>
__global__ __launch_bounds__(256) void gemm_kernel(
    const float* __restrict__ A, int lda,
    const float* __restrict__ Bw, int ldb,
    const float* __restrict__ bias,
    const float* res,           // no restrict: may alias C
    float* C, int ldc,
    int N, int K) {
  __shared__ float As[BK][BM];
  __shared__ float Bs[BK][BN];
  const int tid = threadIdx.x;
  const int m0 = blockIdx.x * BM;
  const int n0 = blockIdx.y * BN;
  constexpr int MT = BM / TM;
  const int tm0 = (tid % MT) * TM;
  const int tn0 = (tid / MT) * TN;
  constexpr int K4 = BK / 4;
  constexpr int A_LOADS = BM * BK / 4 / 256;
  constexpr int B_LOADS = BN * BK / 4 / 256;

  float acc[TM][TN] = {};

  for (int k0 = 0; k0 < K; k0 += BK) {
#pragma unroll
    for (int i = 0; i < A_LOADS; i++) {
      int id = tid + i * 256;
      int row = id / K4, kc = (id % K4) * 4;
      float4 v = make_float4(0.f, 0.f, 0.f, 0.f);
      if (k0 + kc < K)
        v = *(const float4*)(A + (size_t)(m0 + row) * lda + k0 + kc);
      As[kc + 0][row] = v.x; As[kc + 1][row] = v.y;
      As[kc + 2][row] = v.z; As[kc + 3][row] = v.w;
    }
#pragma unroll
    for (int i = 0; i < B_LOADS; i++) {
      int id = tid + i * 256;
      int row = id / K4, kc = (id % K4) * 4;
      float4 v = make_float4(0.f, 0.f, 0.f, 0.f);
      if ((n0 + row) < N && (k0 + kc) < K)
        v = *(const float4*)(Bw + (size_t)(n0 + row) * ldb + k0 + kc);
      Bs[kc + 0][row] = v.x; Bs[kc + 1][row] = v.y;
      Bs[kc + 2][row] = v.z; Bs[kc + 3][row] = v.w;
    }
    __syncthreads();
#pragma unroll
    for (int k = 0; k < BK; k++) {
      float a[TM], bb[TN];
#pragma unroll
      for (int i = 0; i < TM; i++) a[i] = As[k][tm0 + i];
#pragma unroll
      for (int j = 0; j < TN; j++) bb[j] = Bs[k][tn0 + j];
#pragma unroll
      for (int i = 0; i < TM; i++)
#pragma unroll
        for (int j = 0; j < TN; j++) acc[i][j] += a[i] * bb[j];
    }
    __syncthreads();
  }

#pragma unroll
  for (int i = 0; i < TM; i++) {
    int m = m0 + tm0 + i;
#pragma unroll
    for (int j = 0; j < TN; j++) {
      int n = n0 + tn0 + j;
      if (n < N) {
        float v = acc[i][j];
        if (BIAS) v += bias[n];
        if (ACT == 1) v = fmaxf(v, 0.f);
        if (ACT == 2) v = fmaxf(v, 0.f) + log1pf(expf(-fabsf(v)));
        if (RES) v += res[(size_t)m * ldc + n];
        C[(size_t)m * ldc + n] = v;
      }
    }
  }
}

// ---------------- causal depthwise conv (DC=4) + SiLU ----------------
// x part lives in xz[:, 0:DI] (row stride 2*DI)
__global__ __launch_bounds__(256) void conv_silu_kernel(
    const float* __restrict__ xz, const float* __restrict__ cw,
    const float* __restrict__ cb, float* __restrict__ xc) {
  int i = blockIdx.x * 256 + threadIdx.x;   // over M_ROWS*DI
  int row = i / DI, d = i - row * DI;
  int t = row % T;
  float acc = cb[d];
#pragma unroll
  for (int k = 0; k < DC; k++) {
    int tt = t + k - (DC - 1);
    if (tt >= 0)
      acc += xz[(size_t)(row + k - (DC - 1)) * (2 * DI) + d] * cw[d * DC + k];
  }
  float sg = 1.f / (1.f + expf(-acc));
  xc[i] = acc * sg;
}

// ---------------- selective scan ----------------
// lane = (channel c, state s): 16 channels x 16 states per block of 256.
// y may alias dt (read-before-write within the owning 16-lane group).
__global__ __launch_bounds__(256) void scan_kernel(
    const float* __restrict__ xc,   // [M_ROWS, DI]
    const float* __restrict__ xdbl, // [M_ROWS, 56]
    const float* dt,                // [M_ROWS, DI]  (no restrict: aliases y)
    const float* __restrict__ xz,   // [M_ROWS, 2*DI] (z part)
    const float* __restrict__ A_log,// [DI, DS]
    const float* __restrict__ Dskip,// [DI]
    float* y) {                     // [M_ROWS, DI]
  int c = threadIdx.x >> 4;
  int s = threadIdx.x & 15;
  int d0 = (blockIdx.x % (DI / 16)) * 16;
  int b = blockIdx.x / (DI / 16);
  int d = d0 + c;
  float Av = -expf(A_log[d * DS + s]);
  float Dp = Dskip[d];
  float h = 0.f;
  size_t rbase = (size_t)b * T;
  for (int t = 0; t < T; t++) {
    size_t row = rbase + t;
    float dtv = dt[row * DI + d];
    float xv = xc[row * DI + d];
    float Bv = xdbl[row * 56 + 24 + s];
    float Cv = xdbl[row * 56 + 40 + s];
    float dA = expf(dtv * Av);
    h = dA * h + dtv * xv * Bv;
    float p = h * Cv;
    p += __shfl_xor(p, 1, 64);
    p += __shfl_xor(p, 2, 64);
    p += __shfl_xor(p, 4, 64);
    p += __shfl_xor(p, 8, 64);
    if (s == 0) {
      float zv = xz[row * (2 * DI) + DI + d];
      float sg = 1.f / (1.f + expf(-zv));
      y[row * DI + d] = (p + xv * Dp) * (zv * sg);
    }
  }
}

// ---------------- loss ----------------
__global__ __launch_bounds__(256) void loss_rows_kernel(
    const float* __restrict__ logits, const int* __restrict__ tgt,
    float* __restrict__ partials) {
  int wave = threadIdx.x >> 6, lane = threadIdx.x & 63;
  int row = blockIdx.x * 4 + wave;
  const float* p = logits + (size_t)row * V;
  float v0 = (lane < V) ? p[lane] : -INFINITY;
  float v1 = (lane + 64 < V) ? p[lane + 64] : -INFINITY;
  float mx = fmaxf(v0, v1);
#pragma unroll
  for (int o = 1; o < 64; o <<= 1) mx = fmaxf(mx, __shfl_xor(mx, o, 64));
  float e = ((lane < V) ? expf(v0 - mx) : 0.f) +
            ((lane + 64 < V) ? expf(v1 - mx) : 0.f);
#pragma unroll
  for (int o = 1; o < 64; o <<= 1) e += __shfl_xor(e, o, 64);
  float lse = mx + logf(e);
  __shared__ float sm[4];
  if (lane == 0) sm[wave] = lse - p[tgt[row]];
  __syncthreads();
  if (threadIdx.x == 0)
    partials[blockIdx.x] = sm[0] + sm[1] + sm[2] + sm[3];
}

__global__ __launch_bounds__(256) void loss_final_kernel(
    const float* __restrict__ partials, float* __restrict__ out) {
  double s = 0.0;
  for (int i = threadIdx.x; i < 4096; i += 256) s += (double)partials[i];
  __shared__ double sm[256];
  sm[threadIdx.x] = s;
  __syncthreads();
  for (int st = 128; st > 0; st >>= 1) {
    if (threadIdx.x < st) sm[threadIdx.x] += sm[threadIdx.x + st];
    __syncthreads();
  }
  if (threadIdx.x == 0) out[0] = (float)(sm[0] / (double)(B * T));
}

// ---------------- host launch ----------------
extern "C" void kernel_launch(void* const* d_in, const int* in_sizes, int n_in,
                              void* d_out, int out_size, void* d_ws,
                              size_t ws_size, hipStream_t stream) {
  const int* idx = (const int*)d_in[0];
  const int* tgt = (const int*)d_in[1];
  const float* tok = (const float*)d_in[2];
  const float* pos = (const float*)d_in[3];
  const float* ln1g = (const float*)d_in[4];
  const float* ln1b = (const float*)d_in[5];
  const float* inw = (const float*)d_in[6];
  const float* convw = (const float*)d_in[7];
  const float* convb = (const float*)d_in[8];
  const float* xpw = (const float*)d_in[9];
  const float* dtpw = (const float*)d_in[10];
  const float* dtpb = (const float*)d_in[11];
  const float* alog = (const float*)d_in[12];
  const float* dskip = (const float*)d_in[13];
  const float* outw = (const float*)d_in[14];
  const float* ln2g = (const float*)d_in[15];
  const float* ln2b = (const float*)d_in[16];
  const float* w1 = (const float*)d_in[17];
  const float* b1 = (const float*)d_in[18];
  const float* w2 = (const float*)d_in[19];
  const float* b2 = (const float*)d_in[20];
  const float* lnfg = (const float*)d_in[21];
  const float* lnfb = (const float*)d_in[22];
  const float* hw = (const float*)d_in[23];
  const float* hb = (const float*)d_in[24];
  float* out = (float*)d_out;

  char* ws = (char*)d_ws;
  size_t o = 0;
  float* x = (float*)(ws + o);   o += (size_t)M_ROWS * D * 4;       // 25.2 MB
  float* u = (float*)(ws + o);   o += (size_t)M_ROWS * D * 4;       // 25.2 MB
  float* xzb = (float*)(ws + o); o += (size_t)M_ROWS * 2 * DI * 4;  // 100.7 MB
  float* xcb = (float*)(ws + o); o += (size_t)M_ROWS * DI * 4;      // 50.3 MB
  float* xdb = (float*)(ws + o); o += (size_t)M_ROWS * 56 * 4;      // 3.7 MB
  float* dtb = (float*)(ws + o); o += (size_t)M_ROWS * DI * 4;      // 50.3 MB
  float* part = (float*)(ws + o);                                   // 16 KB
  float* yb = dtb;  // alias: scan reads dt[row,d] before writing y[row,d]

  embed_kernel<<<M_ROWS * D / 256, 256, 0, stream>>>(idx, tok, pos, x);

  for (int l = 0; l < NL; l++) {
    ln_kernel<<<M_ROWS / 4, 256, 0, stream>>>(x, ln1g + l * D, ln1b + l * D, u);
    // xz = u @ in_w^T   [16384,1536] K=384
    gemm_kernel<128, 128, 16, 8, 8, 0, false, false>
        <<<dim3(M_ROWS / 128, 12), 256, 0, stream>>>(
            u, D, inw + (size_t)l * 2 * DI * D, D, nullptr, nullptr, xzb,
            2 * DI, 2 * DI, D);
    conv_silu_kernel<<<M_ROWS * DI / 256, 256, 0, stream>>>(
        xzb, convw + (size_t)l * DI * DC, convb + (size_t)l * DI, xcb);
    // x_dbl = xc @ xp_w^T   [16384,56] K=768
    gemm_kernel<64, 64, 16, 4, 4, 0, false, false>
        <<<dim3(M_ROWS / 64, 1), 256, 0, stream>>>(
            xcb, DI, xpw + (size_t)l * (DTR + 2 * DS) * DI, DI, nullptr,
            nullptr, xdb, 56, 56, DI);
    // dt = softplus(x_dbl[:, :24] @ dtp_w^T + b)   [16384,768] K=24
    gemm_kernel<128, 128, 16, 8, 8, 2, true, false>
        <<<dim3(M_ROWS / 128, 6), 256, 0, stream>>>(
            xdb, 56, dtpw + (size_t)l * DI * DTR, DTR, dtpb + (size_t)l * DI,
            nullptr, dtb, DI, DI, DTR);
    scan_kernel<<<B * (DI / 16), 256, 0, stream>>>(
        xcb, xdb, dtb, xzb, alog + (size_t)l * DI * DS, dskip + (size_t)l * DI,
        yb);
    // x += y @ out_w^T   [16384,384] K=768
    gemm_kernel<128, 128, 16, 8, 8, 0, false, true>
        <<<dim3(M_ROWS / 128, 3), 256, 0, stream>>>(
            yb, DI, outw + (size_t)l * D * DI, DI, nullptr, x, x, D, D, DI);
    ln_kernel<<<M_ROWS / 4, 256, 0, stream>>>(x, ln2g + l * D, ln2b + l * D, u);
    // h = relu(u @ w1^T + b1)   [16384,1536] K=384
    gemm_kernel<128, 128, 16, 8, 8, 1, true, false>
        <<<dim3(M_ROWS / 128, 12), 256, 0, stream>>>(
            u, D, w1 + (size_t)l * DFF * D, D, b1 + (size_t)l * DFF, nullptr,
            xzb, DFF, DFF, D);
    // x += h @ w2^T + b2   [16384,384] K=1536
    gemm_kernel<128, 128, 16, 8, 8, 0, true, true>
        <<<dim3(M_ROWS / 128, 3), 256, 0, stream>>>(
            xzb, DFF, w2 + (size_t)l * D * DFF, DFF, b2 + (size_t)l * D, x, x,
            D, D, DFF);
  }

  ln_kernel<<<M_ROWS / 4, 256, 0, stream>>>(x, lnfg, lnfb, u);
  // logits = u @ head_w^T + head_b   [16384,65] K=384
  gemm_kernel<64, 64, 16, 4, 4, 0, true, false>
      <<<dim3(M_ROWS / 64, 2), 256, 0, stream>>>(u, D, hw, D, hb, nullptr, out,
                                                 V, V, D);
  loss_rows_kernel<<<M_ROWS / 4, 256, 0, stream>>>(out, tgt, part);
  loss_final_kernel<<<1, 256, 0, stream>>>(part, out + (size_t)M_ROWS * V);
}

// Round 4
// 12211.232 us; speedup vs baseline: 1.6910x; 1.6910x over previous
//
#include <hip/hip_runtime.h>
#include <hip/hip_bf16.h>
#include <math.h>

#define V 65
#define D 384
#define NL 12
#define T 512
#define B 32
#define DI 768
#define DS 16
#define DC 4
#define DTR 24
#define DFF 1536
#define EPS 1e-5f
#define M_ROWS (B*T)   // 16384

typedef __bf16 bf16_t;
typedef bf16_t bf16x4_t __attribute__((ext_vector_type(4)));
typedef bf16_t bf16x8_t __attribute__((ext_vector_type(8)));
typedef float f32x4_t __attribute__((ext_vector_type(4)));

// swizzled element index in a [128][64] bf16 LDS tile: XOR 8-elem slot by row&7
// (breaks the 16-way bank conflict of the 128B-stride column read; write side
// uses the same involution so read/write agree)
#define SWZ64(row, k) (((row) << 6) + ((k) ^ (((row) & 7) << 3)))

// ---------------- embedding ----------------
__global__ __launch_bounds__(256) void embed_kernel(
    const int* __restrict__ idx, const float* __restrict__ tok,
    const float* __restrict__ pos, float* __restrict__ x) {
  int i = blockIdx.x * 256 + threadIdx.x;
  int row = i / D, d = i - row * D;
  int t = row % T;
  x[i] = tok[idx[row] * D + d] + pos[t * D + d];
}

// ---------------- layernorm (1 wave per row of D=384) ----------------
__global__ __launch_bounds__(256) void ln_kernel(
    const float* __restrict__ in, const float* __restrict__ g,
    const float* __restrict__ b, float* __restrict__ out) {
  int wave = threadIdx.x >> 6;
  int lane = threadIdx.x & 63;
  int row = blockIdx.x * 4 + wave;
  const float* p = in + (size_t)row * D;
  float v[6];
  float s = 0.f, ss = 0.f;
#pragma unroll
  for (int i = 0; i < 6; i++) {
    v[i] = p[lane + i * 64];
    s += v[i];
    ss += v[i] * v[i];
  }
#pragma unroll
  for (int o = 1; o < 64; o <<= 1) {
    s += __shfl_xor(s, o, 64);
    ss += __shfl_xor(ss, o, 64);
  }
  float mu = s * (1.f / D);
  float var = ss * (1.f / D) - mu * mu;
  float rs = rsqrtf(var + EPS);
  float* q = out + (size_t)row * D;
#pragma unroll
  for (int i = 0; i < 6; i++) {
    int d = lane + i * 64;
    q[d] = (v[i] - mu) * rs * g[d] + b[d];
  }
}

// ---------------- bf16x3-split MFMA GEMM ----------------
// C[M,N] = A[M,K] @ Bw[N,K]^T via split A=Ah+Al, B=Bh+Bl (bf16),
// C ~= Ah*Bh + Al*Bh + Ah*Bl.  BM=BN=128, BK=64, 4 waves, each wave 64x64.
// ACT: 0 none, 1 relu, 2 softplus. Epilogue: bias -> act -> +res.
template <int ACT, bool BIAS, bool RES>
__global__ __launch_bounds__(256) void gemm_mfma_kernel(
    const float* __restrict__ A, int lda,
    const float* __restrict__ Bw, int ldb,
    const float* __restrict__ bias,
    const float* res,            // may alias C
    float* C, int ldc, int K) {
  __shared__ bf16_t Ah[128 * 64];
  __shared__ bf16_t Al[128 * 64];
  __shared__ bf16_t Bh[128 * 64];
  __shared__ bf16_t Bl[128 * 64];
  const int tid = threadIdx.x;
  const int m0 = blockIdx.x * 128, n0 = blockIdx.y * 128;
  const int lane = tid & 63, w = tid >> 6;
  const int wm = (w >> 1) * 64, wn = (w & 1) * 64;
  const float* Abase = A + (size_t)m0 * lda;
  const float* Bbase = Bw + (size_t)n0 * ldb;

  f32x4_t acc[4][4] = {};

  for (int k0 = 0; k0 < K; k0 += 64) {
    // ---- stage A,B tiles fp32 -> (hi,lo) bf16 in swizzled LDS ----
#pragma unroll
    for (int i = 0; i < 8; i++) {
      int q = tid + (i << 8);
      int row = q >> 4, kc = (q & 15) << 2;
      float4 va = make_float4(0.f, 0.f, 0.f, 0.f);
      float4 vb = make_float4(0.f, 0.f, 0.f, 0.f);
      if (k0 + kc < K) {
        va = *(const float4*)(Abase + (size_t)row * lda + k0 + kc);
        vb = *(const float4*)(Bbase + (size_t)row * ldb + k0 + kc);
      }
      bf16x4_t ah, al, bh, bl;
      float f;
      ah[0] = (bf16_t)va.x; f = (float)ah[0]; al[0] = (bf16_t)(va.x - f);
      ah[1] = (bf16_t)va.y; f = (float)ah[1]; al[1] = (bf16_t)(va.y - f);
      ah[2] = (bf16_t)va.z; f = (float)ah[2]; al[2] = (bf16_t)(va.z - f);
      ah[3] = (bf16_t)va.w; f = (float)ah[3]; al[3] = (bf16_t)(va.w - f);
      bh[0] = (bf16_t)vb.x; f = (float)bh[0]; bl[0] = (bf16_t)(vb.x - f);
      bh[1] = (bf16_t)vb.y; f = (float)bh[1]; bl[1] = (bf16_t)(vb.y - f);
      bh[2] = (bf16_t)vb.z; f = (float)bh[2]; bl[2] = (bf16_t)(vb.z - f);
      bh[3] = (bf16_t)vb.w; f = (float)bh[3]; bl[3] = (bf16_t)(vb.w - f);
      int o = SWZ64(row, kc);
      *(bf16x4_t*)&Ah[o] = ah;
      *(bf16x4_t*)&Al[o] = al;
      *(bf16x4_t*)&Bh[o] = bh;
      *(bf16x4_t*)&Bl[o] = bl;
    }
    __syncthreads();
    // ---- MFMA over the K-tile (2 k-slices of 32) ----
#pragma unroll
    for (int ks = 0; ks < 2; ks++) {
      int kk = ks * 32 + ((lane >> 4) << 3);
      bf16x8_t a_h[4], a_l[4], b_h[4], b_l[4];
#pragma unroll
      for (int f = 0; f < 4; f++) {
        int ra = wm + f * 16 + (lane & 15);
        int rb = wn + f * 16 + (lane & 15);
        a_h[f] = *(bf16x8_t*)&Ah[SWZ64(ra, kk)];
        a_l[f] = *(bf16x8_t*)&Al[SWZ64(ra, kk)];
        b_h[f] = *(bf16x8_t*)&Bh[SWZ64(rb, kk)];
        b_l[f] = *(bf16x8_t*)&Bl[SWZ64(rb, kk)];
      }
#pragma unroll
      for (int mf = 0; mf < 4; mf++)
#pragma unroll
        for (int nf = 0; nf < 4; nf++) {
          acc[mf][nf] = __builtin_amdgcn_mfma_f32_16x16x32_bf16(
              a_h[mf], b_h[nf], acc[mf][nf], 0, 0, 0);
          acc[mf][nf] = __builtin_amdgcn_mfma_f32_16x16x32_bf16(
              a_l[mf], b_h[nf], acc[mf][nf], 0, 0, 0);
          acc[mf][nf] = __builtin_amdgcn_mfma_f32_16x16x32_bf16(
              a_h[mf], b_l[nf], acc[mf][nf], 0, 0, 0);
        }
    }
    __syncthreads();
  }

  // ---- epilogue: C/D layout row=(lane>>4)*4+j, col=lane&15 ----
  const int rbase = m0 + wm + ((lane >> 4) << 2);
  const int cbase = n0 + wn + (lane & 15);
#pragma unroll
  for (int mf = 0; mf < 4; mf++)
#pragma unroll
    for (int nf = 0; nf < 4; nf++) {
      int n = cbase + nf * 16;
      float bv = BIAS ? bias[n] : 0.f;
#pragma unroll
      for (int j = 0; j < 4; j++) {
        int m = rbase + mf * 16 + j;
        float v = acc[mf][nf][j];
        if (BIAS) v += bv;
        if (ACT == 1) v = fmaxf(v, 0.f);
        if (ACT == 2) v = fmaxf(v, 0.f) + log1pf(expf(-fabsf(v)));
        if (RES) v += res[(size_t)m * ldc + n];
        C[(size_t)m * ldc + n] = v;
      }
    }
}

// ---------------- small fp32 VALU GEMM (x_proj N=56, head N=65) ----------------
template <int BM, int BN, int BK, int TM, int TN, int ACT, bool BIAS, bool RES>
__global__ __launch_bounds__(256) void gemm_kernel(
    const float* __restrict__ A, int lda,
    const float* __restrict__ Bw, int ldb,
    const float* __restrict__ bias,
    const float* res, float* C, int ldc,
    int N, int K) {
  __shared__ float As[BK][BM];
  __shared__ float Bs[BK][BN];
  const int tid = threadIdx.x;
  const int m0 = blockIdx.x * BM;
  const int n0 = blockIdx.y * BN;
  constexpr int MT = BM / TM;
  const int tm0 = (tid % MT) * TM;
  const int tn0 = (tid / MT) * TN;
  constexpr int K4 = BK / 4;
  constexpr int A_LOADS = BM * BK / 4 / 256;
  constexpr int B_LOADS = BN * BK / 4 / 256;

  float acc[TM][TN] = {};

  for (int k0 = 0; k0 < K; k0 += BK) {
#pragma unroll
    for (int i = 0; i < A_LOADS; i++) {
      int id = tid + i * 256;
      int row = id / K4, kc = (id % K4) * 4;
      float4 v = make_float4(0.f, 0.f, 0.f, 0.f);
      if (k0 + kc < K)
        v = *(const float4*)(A + (size_t)(m0 + row) * lda + k0 + kc);
      As[kc + 0][row] = v.x; As[kc + 1][row] = v.y;
      As[kc + 2][row] = v.z; As[kc + 3][row] = v.w;
    }
#pragma unroll
    for (int i = 0; i < B_LOADS; i++) {
      int id = tid + i * 256;
      int row = id / K4, kc = (id % K4) * 4;
      float4 v = make_float4(0.f, 0.f, 0.f, 0.f);
      if ((n0 + row) < N && (k0 + kc) < K)
        v = *(const float4*)(Bw + (size_t)(n0 + row) * ldb + k0 + kc);
      Bs[kc + 0][row] = v.x; Bs[kc + 1][row] = v.y;
      Bs[kc + 2][row] = v.z; Bs[kc + 3][row] = v.w;
    }
    __syncthreads();
#pragma unroll
    for (int k = 0; k < BK; k++) {
      float a[TM], bb[TN];
#pragma unroll
      for (int i = 0; i < TM; i++) a[i] = As[k][tm0 + i];
#pragma unroll
      for (int j = 0; j < TN; j++) bb[j] = Bs[k][tn0 + j];
#pragma unroll
      for (int i = 0; i < TM; i++)
#pragma unroll
        for (int j = 0; j < TN; j++) acc[i][j] += a[i] * bb[j];
    }
    __syncthreads();
  }

#pragma unroll
  for (int i = 0; i < TM; i++) {
    int m = m0 + tm0 + i;
#pragma unroll
    for (int j = 0; j < TN; j++) {
      int n = n0 + tn0 + j;
      if (n < N) {
        float v = acc[i][j];
        if (BIAS) v += bias[n];
        if (ACT == 1) v = fmaxf(v, 0.f);
        if (ACT == 2) v = fmaxf(v, 0.f) + log1pf(expf(-fabsf(v)));
        if (RES) v += res[(size_t)m * ldc + n];
        C[(size_t)m * ldc + n] = v;
      }
    }
  }
}

// ---------------- causal depthwise conv (DC=4) + SiLU; also silu(z) in-place ----
// x part lives in xz[:, 0:DI]; z part xz[:, DI:2*DI] is overwritten with silu(z).
__global__ __launch_bounds__(256) void conv_silu_kernel(
    float* xz, const float* __restrict__ cw,
    const float* __restrict__ cb, float* __restrict__ xc) {
  int i = blockIdx.x * 256 + threadIdx.x;   // over M_ROWS*DI
  int row = i / DI, d = i - row * DI;
  int t = row % T;
  float acc = cb[d];
#pragma unroll
  for (int k = 0; k < DC; k++) {
    int tt = t + k - (DC - 1);
    if (tt >= 0)
      acc += xz[(size_t)(row + k - (DC - 1)) * (2 * DI) + d] * cw[d * DC + k];
  }
  float sg = 1.f / (1.f + __expf(-acc));
  xc[i] = acc * sg;
  // silu(z) in place (own element only; conv taps never read the z half)
  size_t zi = (size_t)row * (2 * DI) + DI + d;
  float zv = xz[zi];
  xz[zi] = zv / (1.f + __expf(-zv));
}

// ---------------- selective scan ----------------
// lane = (channel c, state s): 16 channels x 16 states per block of 256.
// y aliases dt (write of row t happens after all reads of rows <= t+1 prefetch).
__global__ __launch_bounds__(256) void scan_kernel(
    const float* __restrict__ xc,   // [M_ROWS, DI]
    const float* __restrict__ xdbl, // [M_ROWS, 56]
    const float* dt,                // [M_ROWS, DI]  (aliases y)
    const float* __restrict__ xz,   // [M_ROWS, 2*DI]; z-half holds silu(z)
    const float* __restrict__ A_log,// [DI, DS]
    const float* __restrict__ Dskip,// [DI]
    float* y) {                     // [M_ROWS, DI]
  int c = threadIdx.x >> 4;
  int s = threadIdx.x & 15;
  int d = (blockIdx.x % (DI / 16)) * 16 + c;
  int b = blockIdx.x / (DI / 16);
  float Av = -__expf(A_log[d * DS + s]);
  float Dp = Dskip[d];
  size_t r0 = (size_t)b * T;
  const float* pdt = dt + r0 * DI + d;
  const float* pxc = xc + r0 * DI + d;
  const float* pB = xdbl + r0 * 56 + 24 + s;
  const float* pC = xdbl + r0 * 56 + 40 + s;
  const float* pz = xz + r0 * (2 * DI) + DI + d;
  float* py = y + r0 * DI + d;
  float h = 0.f;
  float dtv = *pdt, xv = *pxc, Bv = *pB, Cv = *pC;
  for (int t = 0; t < T; t++) {
    float dtn = 0.f, xn = 0.f, Bn = 0.f, Cn = 0.f;
    if (t + 1 < T) {  // prefetch next step
      dtn = pdt[DI]; xn = pxc[DI]; Bn = pB[56]; Cn = pC[56];
    }
    float dA = __expf(dtv * Av);
    h = fmaf(dA, h, dtv * xv * Bv);
    float p = h * Cv;
    p += __shfl_xor(p, 1, 64);
    p += __shfl_xor(p, 2, 64);
    p += __shfl_xor(p, 4, 64);
    p += __shfl_xor(p, 8, 64);
    if (s == 0) *py = (p + xv * Dp) * (*pz);
    pdt += DI; pxc += DI; pB += 56; pC += 56; pz += 2 * DI; py += DI;
    dtv = dtn; xv = xn; Bv = Bn; Cv = Cn;
  }
}

// ---------------- loss ----------------
__global__ __launch_bounds__(256) void loss_rows_kernel(
    const float* __restrict__ logits, const int* __restrict__ tgt,
    float* __restrict__ partials) {
  int wave = threadIdx.x >> 6, lane = threadIdx.x & 63;
  int row = blockIdx.x * 4 + wave;
  const float* p = logits + (size_t)row * V;
  float v0 = (lane < V) ? p[lane] : -INFINITY;
  float v1 = (lane + 64 < V) ? p[lane + 64] : -INFINITY;
  float mx = fmaxf(v0, v1);
#pragma unroll
  for (int o = 1; o < 64; o <<= 1) mx = fmaxf(mx, __shfl_xor(mx, o, 64));
  float e = ((lane < V) ? expf(v0 - mx) : 0.f) +
            ((lane + 64 < V) ? expf(v1 - mx) : 0.f);
#pragma unroll
  for (int o = 1; o < 64; o <<= 1) e += __shfl_xor(e, o, 64);
  float lse = mx + logf(e);
  __shared__ float sm[4];
  if (lane == 0) sm[wave] = lse - p[tgt[row]];
  __syncthreads();
  if (threadIdx.x == 0)
    partials[blockIdx.x] = sm[0] + sm[1] + sm[2] + sm[3];
}

__global__ __launch_bounds__(256) void loss_final_kernel(
    const float* __restrict__ partials, float* __restrict__ out) {
  double s = 0.0;
  for (int i = threadIdx.x; i < 4096; i += 256) s += (double)partials[i];
  __shared__ double sm[256];
  sm[threadIdx.x] = s;
  __syncthreads();
  for (int st = 128; st > 0; st >>= 1) {
    if (threadIdx.x < st) sm[threadIdx.x] += sm[threadIdx.x + st];
    __syncthreads();
  }
  if (threadIdx.x == 0) out[0] = (float)(sm[0] / (double)(B * T));
}

// ---------------- host launch ----------------
extern "C" void kernel_launch(void* const* d_in, const int* in_sizes, int n_in,
                              void* d_out, int out_size, void* d_ws,
                              size_t ws_size, hipStream_t stream) {
  const int* idx = (const int*)d_in[0];
  const int* tgt = (const int*)d_in[1];
  const float* tok = (const float*)d_in[2];
  const float* pos = (const float*)d_in[3];
  const float* ln1g = (const float*)d_in[4];
  const float* ln1b = (const float*)d_in[5];
  const float* inw = (const float*)d_in[6];
  const float* convw = (const float*)d_in[7];
  const float* convb = (const float*)d_in[8];
  const float* xpw = (const float*)d_in[9];
  const float* dtpw = (const float*)d_in[10];
  const float* dtpb = (const float*)d_in[11];
  const float* alog = (const float*)d_in[12];
  const float* dskip = (const float*)d_in[13];
  const float* outw = (const float*)d_in[14];
  const float* ln2g = (const float*)d_in[15];
  const float* ln2b = (const float*)d_in[16];
  const float* w1 = (const float*)d_in[17];
  const float* b1 = (const float*)d_in[18];
  const float* w2 = (const float*)d_in[19];
  const float* b2 = (const float*)d_in[20];
  const float* lnfg = (const float*)d_in[21];
  const float* lnfb = (const float*)d_in[22];
  const float* hw = (const float*)d_in[23];
  const float* hb = (const float*)d_in[24];
  float* out = (float*)d_out;

  char* ws = (char*)d_ws;
  size_t o = 0;
  float* x = (float*)(ws + o);   o += (size_t)M_ROWS * D * 4;
  float* u = (float*)(ws + o);   o += (size_t)M_ROWS * D * 4;
  float* xzb = (float*)(ws + o); o += (size_t)M_ROWS * 2 * DI * 4;
  float* xcb = (float*)(ws + o); o += (size_t)M_ROWS * DI * 4;
  float* xdb = (float*)(ws + o); o += (size_t)M_ROWS * 56 * 4;
  float* dtb = (float*)(ws + o); o += (size_t)M_ROWS * DI * 4;
  float* part = (float*)(ws + o);
  float* yb = dtb;  // alias: scan reads dt[row,d] before writing y[row,d]

  embed_kernel<<<M_ROWS * D / 256, 256, 0, stream>>>(idx, tok, pos, x);

  for (int l = 0; l < NL; l++) {
    ln_kernel<<<M_ROWS / 4, 256, 0, stream>>>(x, ln1g + l * D, ln1b + l * D, u);
    // xz = u @ in_w^T   [16384,1536] K=384
    gemm_mfma_kernel<0, false, false><<<dim3(M_ROWS / 128, 12), 256, 0, stream>>>(
        u, D, inw + (size_t)l * 2 * DI * D, D, nullptr, nullptr, xzb, 2 * DI, D);
    conv_silu_kernel<<<M_ROWS * DI / 256, 256, 0, stream>>>(
        xzb, convw + (size_t)l * DI * DC, convb + (size_t)l * DI, xcb);
    // x_dbl = xc @ xp_w^T   [16384,56] K=768  (small-N: VALU gemm)
    gemm_kernel<64, 64, 16, 4, 4, 0, false, false>
        <<<dim3(M_ROWS / 64, 1), 256, 0, stream>>>(
            xcb, DI, xpw + (size_t)l * (DTR + 2 * DS) * DI, DI, nullptr,
            nullptr, xdb, 56, 56, DI);
    // dt = softplus(x_dbl[:, :24] @ dtp_w^T + b)   [16384,768] K=24
    gemm_mfma_kernel<2, true, false><<<dim3(M_ROWS / 128, 6), 256, 0, stream>>>(
        xdb, 56, dtpw + (size_t)l * DI * DTR, DTR, dtpb + (size_t)l * DI,
        nullptr, dtb, DI, DTR);
    scan_kernel<<<B * (DI / 16), 256, 0, stream>>>(
        xcb, xdb, dtb, xzb, alog + (size_t)l * DI * DS, dskip + (size_t)l * DI,
        yb);
    // x += y @ out_w^T   [16384,384] K=768
    gemm_mfma_kernel<0, false, true><<<dim3(M_ROWS / 128, 3), 256, 0, stream>>>(
        yb, DI, outw + (size_t)l * D * DI, DI, nullptr, x, x, D, DI);
    ln_kernel<<<M_ROWS / 4, 256, 0, stream>>>(x, ln2g + l * D, ln2b + l * D, u);
    // h = relu(u @ w1^T + b1)   [16384,1536] K=384
    gemm_mfma_kernel<1, true, false><<<dim3(M_ROWS / 128, 12), 256, 0, stream>>>(
        u, D, w1 + (size_t)l * DFF * D, D, b1 + (size_t)l * DFF, nullptr, xzb,
        DFF, D);
    // x += h @ w2^T + b2   [16384,384] K=1536
    gemm_mfma_kernel<0, true, true><<<dim3(M_ROWS / 128, 3), 256, 0, stream>>>(
        xzb, DFF, w2 + (size_t)l * D * DFF, DFF, b2 + (size_t)l * D, x, x, D,
        DFF);
  }

  ln_kernel<<<M_ROWS / 4, 256, 0, stream>>>(x, lnfg, lnfb, u);
  // logits = u @ head_w^T + head_b   [16384,65] K=384
  gemm_kernel<64, 64, 16, 4, 4, 0, true, false>
      <<<dim3(M_ROWS / 64, 2), 256, 0, stream>>>(u, D, hw, D, hb, nullptr, out,
                                                 V, V, D);
  loss_rows_kernel<<<M_ROWS / 4, 256, 0, stream>>>(out, tgt, part);
  loss_final_kernel<<<1, 256, 0, stream>>>(part, out + (size_t)M_ROWS * V);
}

// Round 7
// 8671.853 us; speedup vs baseline: 2.3812x; 1.4081x over previous
//
#include <hip/hip_runtime.h>
#include <hip/hip_bf16.h>
#include <math.h>

#define V 65
#define D 384
#define NL 12
#define T 512
#define B 32
#define DI 768
#define DS 16
#define DC 4
#define DTR 24
#define DFF 1536
#define EPS 1e-5f
#define M_ROWS (B*T)   // 16384
#define NCHUNK 16
#define CLEN (T/NCHUNK)   // 32

typedef __bf16 bf16_t;
typedef bf16_t bf16x4_t __attribute__((ext_vector_type(4)));
typedef bf16_t bf16x8_t __attribute__((ext_vector_type(8)));
typedef float f32x4_t __attribute__((ext_vector_type(4)));

// swizzled element index in a [128][64] bf16 LDS tile: XOR 8-elem slot by row&7
#define SWZ64(row, k) (((row) << 6) + ((k) ^ (((row) & 7) << 3)))

// weight hi/lo buffer offsets (elements) within the rotating per-layer buffer
#define OFF_IN  0
#define OFF_DT  589824
#define OFF_OUT 608256
#define OFF_W1  903168
#define OFF_W2  1492992
#define WTOT    2082816

// ---------------- embedding ----------------
__global__ __launch_bounds__(256) void embed_kernel(
    const int* __restrict__ idx, const float* __restrict__ tok,
    const float* __restrict__ pos, float* __restrict__ x) {
  int i = blockIdx.x * 256 + threadIdx.x;
  int row = i / D, d = i - row * D;
  int t = row % T;
  x[i] = tok[idx[row] * D + d] + pos[t * D + d];
}

// ---------------- fp32 -> (hi,lo) bf16 split ----------------
__global__ __launch_bounds__(256) void cvt_hilo_kernel(
    const float* __restrict__ src, bf16_t* __restrict__ h,
    bf16_t* __restrict__ l, int n) {
  int i = (blockIdx.x * 256 + threadIdx.x) * 4;
  if (i >= n) return;
  float4 v = *(const float4*)(src + i);
  bf16x4_t vh, vl;
  vh[0] = (bf16_t)v.x; vl[0] = (bf16_t)(v.x - (float)vh[0]);
  vh[1] = (bf16_t)v.y; vl[1] = (bf16_t)(v.y - (float)vh[1]);
  vh[2] = (bf16_t)v.z; vl[2] = (bf16_t)(v.z - (float)vh[2]);
  vh[3] = (bf16_t)v.w; vl[3] = (bf16_t)(v.w - (float)vh[3]);
  *(bf16x4_t*)(h + i) = vh;
  *(bf16x4_t*)(l + i) = vl;
}

// ---------------- layernorm (1 wave per row of D=384) ----------------
__global__ __launch_bounds__(256) void ln_kernel(
    const float* __restrict__ in, const float* __restrict__ g,
    const float* __restrict__ b, float* __restrict__ out) {
  int wave = threadIdx.x >> 6;
  int lane = threadIdx.x & 63;
  int row = blockIdx.x * 4 + wave;
  const float* p = in + (size_t)row * D;
  float v[6];
  float s = 0.f, ss = 0.f;
#pragma unroll
  for (int i = 0; i < 6; i++) {
    v[i] = p[lane + i * 64];
    s += v[i];
    ss += v[i] * v[i];
  }
#pragma unroll
  for (int o = 1; o < 64; o <<= 1) {
    s += __shfl_xor(s, o, 64);
    ss += __shfl_xor(ss, o, 64);
  }
  float mu = s * (1.f / D);
  float var = ss * (1.f / D) - mu * mu;
  float rs = rsqrtf(var + EPS);
  float* q = out + (size_t)row * D;
#pragma unroll
  for (int i = 0; i < 6; i++) {
    int d = lane + i * 64;
    q[d] = (v[i] - mu) * rs * g[d] + b[d];
  }
}

// ---------------- bf16x3-split MFMA GEMM, B pre-split ----------------
// C[M,N] = A[M,K] @ Bw[N,K]^T.  A fp32 (split in-kernel); B given as hi/lo bf16.
// BM=BN=128, BK=64, 4 waves. ACT: 0 none, 1 relu, 2 softplus.
template <int ACT, bool BIAS, bool RES>
__global__ __launch_bounds__(256) void gemm_mfma2_kernel(
    const float* __restrict__ A, int lda,
    const bf16_t* __restrict__ Bhg, const bf16_t* __restrict__ Blg, int ldb,
    const float* __restrict__ bias,
    const float* res,            // may alias C
    float* C, int ldc, int K) {
  __shared__ bf16_t Ah[128 * 64];
  __shared__ bf16_t Al[128 * 64];
  __shared__ bf16_t Bh[128 * 64];
  __shared__ bf16_t Bl[128 * 64];
  const int tid = threadIdx.x;
  const int m0 = blockIdx.x * 128, n0 = blockIdx.y * 128;
  const int lane = tid & 63, w = tid >> 6;
  const int wm = (w >> 1) * 64, wn = (w & 1) * 64;
  const float* Abase = A + (size_t)m0 * lda;
  const bf16_t* Bhbase = Bhg + (size_t)n0 * ldb;
  const bf16_t* Blbase = Blg + (size_t)n0 * ldb;

  f32x4_t acc[4][4] = {};

  for (int k0 = 0; k0 < K; k0 += 64) {
    // ---- stage A tile fp32 -> (hi,lo) bf16 ----
#pragma unroll
    for (int i = 0; i < 8; i++) {
      int q = tid + (i << 8);
      int row = q >> 4, kc = (q & 15) << 2;
      float4 va = make_float4(0.f, 0.f, 0.f, 0.f);
      if (k0 + kc < K)
        va = *(const float4*)(Abase + (size_t)row * lda + k0 + kc);
      bf16x4_t ah, al;
      float f;
      ah[0] = (bf16_t)va.x; f = (float)ah[0]; al[0] = (bf16_t)(va.x - f);
      ah[1] = (bf16_t)va.y; f = (float)ah[1]; al[1] = (bf16_t)(va.y - f);
      ah[2] = (bf16_t)va.z; f = (float)ah[2]; al[2] = (bf16_t)(va.z - f);
      ah[3] = (bf16_t)va.w; f = (float)ah[3]; al[3] = (bf16_t)(va.w - f);
      int o = SWZ64(row, kc);
      *(bf16x4_t*)&Ah[o] = ah;
      *(bf16x4_t*)&Al[o] = al;
    }
    // ---- stage B tile: pure bf16x8 copy ----
#pragma unroll
    for (int i = 0; i < 4; i++) {
      int q = tid + (i << 8);            // 0..1023 over 128 rows x 8 col8
      int row = q >> 3, c8 = (q & 7) << 3;
      bf16x8_t vh = {}, vl = {};
      if (k0 + c8 < K) {
        vh = *(const bf16x8_t*)(Bhbase + (size_t)row * ldb + k0 + c8);
        vl = *(const bf16x8_t*)(Blbase + (size_t)row * ldb + k0 + c8);
      }
      int o = SWZ64(row, c8);
      *(bf16x8_t*)&Bh[o] = vh;
      *(bf16x8_t*)&Bl[o] = vl;
    }
    __syncthreads();
    // ---- MFMA over the K-tile (2 k-slices of 32) ----
#pragma unroll
    for (int ks = 0; ks < 2; ks++) {
      int kk = ks * 32 + ((lane >> 4) << 3);
      bf16x8_t a_h[4], a_l[4], b_h[4], b_l[4];
#pragma unroll
      for (int f = 0; f < 4; f++) {
        int ra = wm + f * 16 + (lane & 15);
        int rb = wn + f * 16 + (lane & 15);
        a_h[f] = *(bf16x8_t*)&Ah[SWZ64(ra, kk)];
        a_l[f] = *(bf16x8_t*)&Al[SWZ64(ra, kk)];
        b_h[f] = *(bf16x8_t*)&Bh[SWZ64(rb, kk)];
        b_l[f] = *(bf16x8_t*)&Bl[SWZ64(rb, kk)];
      }
#pragma unroll
      for (int mf = 0; mf < 4; mf++)
#pragma unroll
        for (int nf = 0; nf < 4; nf++) {
          acc[mf][nf] = __builtin_amdgcn_mfma_f32_16x16x32_bf16(
              a_h[mf], b_h[nf], acc[mf][nf], 0, 0, 0);
          acc[mf][nf] = __builtin_amdgcn_mfma_f32_16x16x32_bf16(
              a_l[mf], b_h[nf], acc[mf][nf], 0, 0, 0);
          acc[mf][nf] = __builtin_amdgcn_mfma_f32_16x16x32_bf16(
              a_h[mf], b_l[nf], acc[mf][nf], 0, 0, 0);
        }
    }
    __syncthreads();
  }

  // ---- epilogue: C/D layout row=(lane>>4)*4+j, col=lane&15 ----
  const int rbase = m0 + wm + ((lane >> 4) << 2);
  const int cbase = n0 + wn + (lane & 15);
#pragma unroll
  for (int mf = 0; mf < 4; mf++)
#pragma unroll
    for (int nf = 0; nf < 4; nf++) {
      int n = cbase + nf * 16;
      float bv = BIAS ? bias[n] : 0.f;
#pragma unroll
      for (int j = 0; j < 4; j++) {
        int m = rbase + mf * 16 + j;
        float v = acc[mf][nf][j];
        if (BIAS) v += bv;
        if (ACT == 1) v = fmaxf(v, 0.f);
        if (ACT == 2) v = fmaxf(v, 0.f) + log1pf(expf(-fabsf(v)));
        if (RES) v += res[(size_t)m * ldc + n];
        C[(size_t)m * ldc + n] = v;
      }
    }
}

// ---------------- small fp32 VALU GEMM (x_proj N=56, head N=65) ----------------
template <int BM, int BN, int BK, int TM, int TN, int ACT, bool BIAS, bool RES>
__global__ __launch_bounds__(256) void gemm_kernel(
    const float* __restrict__ A, int lda,
    const float* __restrict__ Bw, int ldb,
    const float* __restrict__ bias,
    const float* res, float* C, int ldc,
    int N, int K) {
  __shared__ float As[BK][BM];
  __shared__ float Bs[BK][BN];
  const int tid = threadIdx.x;
  const int m0 = blockIdx.x * BM;
  const int n0 = blockIdx.y * BN;
  constexpr int MT = BM / TM;
  const int tm0 = (tid % MT) * TM;
  const int tn0 = (tid / MT) * TN;
  constexpr int K4 = BK / 4;
  constexpr int A_LOADS = BM * BK / 4 / 256;
  constexpr int B_LOADS = BN * BK / 4 / 256;

  float acc[TM][TN] = {};

  for (int k0 = 0; k0 < K; k0 += BK) {
#pragma unroll
    for (int i = 0; i < A_LOADS; i++) {
      int id = tid + i * 256;
      int row = id / K4, kc = (id % K4) * 4;
      float4 v = make_float4(0.f, 0.f, 0.f, 0.f);
      if (k0 + kc < K)
        v = *(const float4*)(A + (size_t)(m0 + row) * lda + k0 + kc);
      As[kc + 0][row] = v.x; As[kc + 1][row] = v.y;
      As[kc + 2][row] = v.z; As[kc + 3][row] = v.w;
    }
#pragma unroll
    for (int i = 0; i < B_LOADS; i++) {
      int id = tid + i * 256;
      int row = id / K4, kc = (id % K4) * 4;
      float4 v = make_float4(0.f, 0.f, 0.f, 0.f);
      if ((n0 + row) < N && (k0 + kc) < K)
        v = *(const float4*)(Bw + (size_t)(n0 + row) * ldb + k0 + kc);
      Bs[kc + 0][row] = v.x; Bs[kc + 1][row] = v.y;
      Bs[kc + 2][row] = v.z; Bs[kc + 3][row] = v.w;
    }
    __syncthreads();
#pragma unroll
    for (int k = 0; k < BK; k++) {
      float a[TM], bb[TN];
#pragma unroll
      for (int i = 0; i < TM; i++) a[i] = As[k][tm0 + i];
#pragma unroll
      for (int j = 0; j < TN; j++) bb[j] = Bs[k][tn0 + j];
#pragma unroll
      for (int i = 0; i < TM; i++)
#pragma unroll
        for (int j = 0; j < TN; j++) acc[i][j] += a[i] * bb[j];
    }
    __syncthreads();
  }

#pragma unroll
  for (int i = 0; i < TM; i++) {
    int m = m0 + tm0 + i;
#pragma unroll
    for (int j = 0; j < TN; j++) {
      int n = n0 + tn0 + j;
      if (n < N) {
        float v = acc[i][j];
        if (BIAS) v += bias[n];
        if (ACT == 1) v = fmaxf(v, 0.f);
        if (ACT == 2) v = fmaxf(v, 0.f) + log1pf(expf(-fabsf(v)));
        if (RES) v += res[(size_t)m * ldc + n];
        C[(size_t)m * ldc + n] = v;
      }
    }
  }
}

// ---------------- causal depthwise conv (DC=4) + SiLU; also silu(z) in-place ----
__global__ __launch_bounds__(256) void conv_silu_kernel(
    float* xz, const float* __restrict__ cw,
    const float* __restrict__ cb, float* __restrict__ xc) {
  int i = blockIdx.x * 256 + threadIdx.x;   // over M_ROWS*DI
  int row = i / DI, d = i - row * DI;
  int t = row % T;
  float acc = cb[d];
#pragma unroll
  for (int k = 0; k < DC; k++) {
    int tt = t + k - (DC - 1);
    if (tt >= 0)
      acc += xz[(size_t)(row + k - (DC - 1)) * (2 * DI) + d] * cw[d * DC + k];
  }
  float sg = 1.f / (1.f + __expf(-acc));
  xc[i] = acc * sg;
  size_t zi = (size_t)row * (2 * DI) + DI + d;
  float zv = xz[zi];
  xz[zi] = zv / (1.f + __expf(-zv));
}

// ---------------- chunked selective scan (no cross-lane ops) ----------------
// block = (b, 16 channels); 256 threads = 16 channels x 16 chunks of 32 steps.
// Each thread keeps all DS=16 states in registers.
// pass1: local scan (h0=0), record sum(dt) and h_final per chunk.
// combine: (d,s) threads do 16-step chunk-prefix in LDS (h0 written over hfin).
// pass2: re-scan with correct h0, emit y = (sum_s h*C + x*Dp) * silu(z).
__global__ __launch_bounds__(256) void scan_chunked_kernel(
    const float* __restrict__ xc,   // [M_ROWS, DI]
    const float* __restrict__ xdbl, // [M_ROWS, 56]
    const float* dt,                // [M_ROWS, DI]  (aliases y)
    const float* __restrict__ xz,   // [M_ROWS, 2*DI]; z-half holds silu(z)
    const float* __restrict__ A_log,// [DI, DS]
    const float* __restrict__ Dskip,// [DI]
    float* y) {                     // [M_ROWS, DI]
  __shared__ float hfin[NCHUNK][16][DS];   // 16 KB (becomes h0 after combine)
  __shared__ float sdt[NCHUNK][16];        // 1 KB
  const int tid = threadIdx.x;
  const int dch = tid & 15, ch = tid >> 4;
  const int d0 = (blockIdx.x % (DI / 16)) * 16;
  const int b = blockIdx.x / (DI / 16);
  const int d = d0 + dch;
  float A[DS];
#pragma unroll
  for (int s = 0; s < DS; s++) A[s] = -__expf(A_log[d * DS + s]);
  const size_t rbase = (size_t)b * T + (size_t)ch * CLEN;
  const float* pdt = dt + rbase * DI + d;
  const float* pxc = xc + rbase * DI + d;
  const float* pbc = xdbl + rbase * 56;

  // ---- pass 1 ----
  float h[DS];
#pragma unroll
  for (int s = 0; s < DS; s++) h[s] = 0.f;
  float sd = 0.f;
  for (int t = 0; t < CLEN; t++) {
    float dtv = pdt[(size_t)t * DI];
    float xv = pxc[(size_t)t * DI];
    float bb[DS];
#pragma unroll
    for (int j = 0; j < 4; j++)
      *(float4*)&bb[4 * j] = *(const float4*)(pbc + (size_t)t * 56 + 24 + 4 * j);
    float dx = dtv * xv;
    sd += dtv;
#pragma unroll
    for (int s = 0; s < DS; s++)
      h[s] = fmaf(__expf(dtv * A[s]), h[s], dx * bb[s]);
  }
  sdt[ch][dch] = sd;
#pragma unroll
  for (int s = 0; s < DS; s++) hfin[ch][dch][s] = h[s];
  __syncthreads();

  // ---- combine: thread = (dc, sc) ----
  {
    const int dc = tid >> 4, sc = tid & 15;
    float As = -__expf(A_log[(d0 + dc) * DS + sc]);
    float h0 = 0.f;
#pragma unroll
    for (int c = 0; c < NCHUNK; c++) {
      float hf = hfin[c][dc][sc];
      float P = __expf(As * sdt[c][dc]);
      hfin[c][dc][sc] = h0;            // incoming state for chunk c
      h0 = fmaf(P, h0, hf);
    }
  }
  __syncthreads();

  // ---- pass 2 ----
#pragma unroll
  for (int s = 0; s < DS; s++) h[s] = hfin[ch][dch][s];
  const float Dp = Dskip[d];
  const float* pz = xz + rbase * (2 * DI) + DI + d;
  float* py = y + rbase * DI + d;
  for (int t = 0; t < CLEN; t++) {
    float dtv = pdt[(size_t)t * DI];
    float xv = pxc[(size_t)t * DI];
    float bb[DS], cc[DS];
#pragma unroll
    for (int j = 0; j < 4; j++) {
      *(float4*)&bb[4 * j] = *(const float4*)(pbc + (size_t)t * 56 + 24 + 4 * j);
      *(float4*)&cc[4 * j] = *(const float4*)(pbc + (size_t)t * 56 + 40 + 4 * j);
    }
    float dx = dtv * xv;
    float acc = 0.f;
#pragma unroll
    for (int s = 0; s < DS; s++) {
      h[s] = fmaf(__expf(dtv * A[s]), h[s], dx * bb[s]);
      acc = fmaf(h[s], cc[s], acc);
    }
    float yv = (acc + xv * Dp) * pz[(size_t)t * 2 * DI];
    py[(size_t)t * DI] = yv;
  }
}

// ---------------- loss ----------------
__global__ __launch_bounds__(256) void loss_rows_kernel(
    const float* __restrict__ logits, const int* __restrict__ tgt,
    float* __restrict__ partials) {
  int wave = threadIdx.x >> 6, lane = threadIdx.x & 63;
  int row = blockIdx.x * 4 + wave;
  const float* p = logits + (size_t)row * V;
  float v0 = (lane < V) ? p[lane] : -INFINITY;
  float v1 = (lane + 64 < V) ? p[lane + 64] : -INFINITY;
  float mx = fmaxf(v0, v1);
#pragma unroll
  for (int o = 1; o < 64; o <<= 1) mx = fmaxf(mx, __shfl_xor(mx, o, 64));
  float e = ((lane < V) ? expf(v0 - mx) : 0.f) +
            ((lane + 64 < V) ? expf(v1 - mx) : 0.f);
#pragma unroll
  for (int o = 1; o < 64; o <<= 1) e += __shfl_xor(e, o, 64);
  float lse = mx + logf(e);
  __shared__ float sm[4];
  if (lane == 0) sm[wave] = lse - p[tgt[row]];
  __syncthreads();
  if (threadIdx.x == 0)
    partials[blockIdx.x] = sm[0] + sm[1] + sm[2] + sm[3];
}

__global__ __launch_bounds__(256) void loss_final_kernel(
    const float* __restrict__ partials, float* __restrict__ out) {
  double s = 0.0;
  for (int i = threadIdx.x; i < 4096; i += 256) s += (double)partials[i];
  __shared__ double sm[256];
  sm[threadIdx.x] = s;
  __syncthreads();
  for (int st = 128; st > 0; st >>= 1) {
    if (threadIdx.x < st) sm[threadIdx.x] += sm[threadIdx.x + st];
    __syncthreads();
  }
  if (threadIdx.x == 0) out[0] = (float)(sm[0] / (double)(B * T));
}

// ---------------- host launch ----------------
extern "C" void kernel_launch(void* const* d_in, const int* in_sizes, int n_in,
                              void* d_out, int out_size, void* d_ws,
                              size_t ws_size, hipStream_t stream) {
  const int* idx = (const int*)d_in[0];
  const int* tgt = (const int*)d_in[1];
  const float* tok = (const float*)d_in[2];
  const float* pos = (const float*)d_in[3];
  const float* ln1g = (const float*)d_in[4];
  const float* ln1b = (const float*)d_in[5];
  const float* inw = (const float*)d_in[6];
  const float* convw = (const float*)d_in[7];
  const float* convb = (const float*)d_in[8];
  const float* xpw = (const float*)d_in[9];
  const float* dtpw = (const float*)d_in[10];
  const float* dtpb = (const float*)d_in[11];
  const float* alog = (const float*)d_in[12];
  const float* dskip = (const float*)d_in[13];
  const float* outw = (const float*)d_in[14];
  const float* ln2g = (const float*)d_in[15];
  const float* ln2b = (const float*)d_in[16];
  const float* w1 = (const float*)d_in[17];
  const float* b1 = (const float*)d_in[18];
  const float* w2 = (const float*)d_in[19];
  const float* b2 = (const float*)d_in[20];
  const float* lnfg = (const float*)d_in[21];
  const float* lnfb = (const float*)d_in[22];
  const float* hw = (const float*)d_in[23];
  const float* hb = (const float*)d_in[24];
  float* out = (float*)d_out;

  char* ws = (char*)d_ws;
  size_t o = 0;
  float* x = (float*)(ws + o);   o += (size_t)M_ROWS * D * 4;
  float* u = (float*)(ws + o);   o += (size_t)M_ROWS * D * 4;
  float* xzb = (float*)(ws + o); o += (size_t)M_ROWS * 2 * DI * 4;
  float* xcb = (float*)(ws + o); o += (size_t)M_ROWS * DI * 4;
  float* xdb = (float*)(ws + o); o += (size_t)M_ROWS * 56 * 4;
  float* dtb = (float*)(ws + o); o += (size_t)M_ROWS * DI * 4;
  float* part = (float*)(ws + o); o += 4096 * 4;
  bf16_t* wh = (bf16_t*)(ws + o); o += (size_t)WTOT * 2;
  bf16_t* wl = (bf16_t*)(ws + o); o += (size_t)WTOT * 2;
  float* yb = dtb;  // alias: scan pass2 reads dt[row,d] before writing y[row,d]

  embed_kernel<<<M_ROWS * D / 256, 256, 0, stream>>>(idx, tok, pos, x);

  for (int l = 0; l < NL; l++) {
    // pre-split this layer's weights into (hi,lo) bf16
    cvt_hilo_kernel<<<576, 256, 0, stream>>>(inw + (size_t)l * 2 * DI * D,
                                             wh + OFF_IN, wl + OFF_IN, 589824);
    cvt_hilo_kernel<<<18, 256, 0, stream>>>(dtpw + (size_t)l * DI * DTR,
                                            wh + OFF_DT, wl + OFF_DT, 18432);
    cvt_hilo_kernel<<<288, 256, 0, stream>>>(outw + (size_t)l * D * DI,
                                             wh + OFF_OUT, wl + OFF_OUT, 294912);
    cvt_hilo_kernel<<<576, 256, 0, stream>>>(w1 + (size_t)l * DFF * D,
                                             wh + OFF_W1, wl + OFF_W1, 589824);
    cvt_hilo_kernel<<<576, 256, 0, stream>>>(w2 + (size_t)l * D * DFF,
                                             wh + OFF_W2, wl + OFF_W2, 589824);

    ln_kernel<<<M_ROWS / 4, 256, 0, stream>>>(x, ln1g + l * D, ln1b + l * D, u);
    // xz = u @ in_w^T   [16384,1536] K=384
    gemm_mfma2_kernel<0, false, false>
        <<<dim3(M_ROWS / 128, 12), 256, 0, stream>>>(
            u, D, wh + OFF_IN, wl + OFF_IN, D, nullptr, nullptr, xzb, 2 * DI, D);
    conv_silu_kernel<<<M_ROWS * DI / 256, 256, 0, stream>>>(
        xzb, convw + (size_t)l * DI * DC, convb + (size_t)l * DI, xcb);
    // x_dbl = xc @ xp_w^T   [16384,56] K=768  (small-N: VALU gemm)
    gemm_kernel<64, 64, 16, 4, 4, 0, false, false>
        <<<dim3(M_ROWS / 64, 1), 256, 0, stream>>>(
            xcb, DI, xpw + (size_t)l * (DTR + 2 * DS) * DI, DI, nullptr,
            nullptr, xdb, 56, 56, DI);
    // dt = softplus(x_dbl[:, :24] @ dtp_w^T + b)   [16384,768] K=24
    gemm_mfma2_kernel<2, true, false>
        <<<dim3(M_ROWS / 128, 6), 256, 0, stream>>>(
            xdb, 56, wh + OFF_DT, wl + OFF_DT, DTR, dtpb + (size_t)l * DI,
            nullptr, dtb, DI, DTR);
    scan_chunked_kernel<<<B * (DI / 16), 256, 0, stream>>>(
        xcb, xdb, dtb, xzb, alog + (size_t)l * DI * DS, dskip + (size_t)l * DI,
        yb);
    // x += y @ out_w^T   [16384,384] K=768
    gemm_mfma2_kernel<0, false, true>
        <<<dim3(M_ROWS / 128, 3), 256, 0, stream>>>(
            yb, DI, wh + OFF_OUT, wl + OFF_OUT, DI, nullptr, x, x, D, DI);
    ln_kernel<<<M_ROWS / 4, 256, 0, stream>>>(x, ln2g + l * D, ln2b + l * D, u);
    // h = relu(u @ w1^T + b1)   [16384,1536] K=384
    gemm_mfma2_kernel<1, true, false>
        <<<dim3(M_ROWS / 128, 12), 256, 0, stream>>>(
            u, D, wh + OFF_W1, wl + OFF_W1, D, b1 + (size_t)l * DFF, nullptr,
            xzb, DFF, D);
    // x += h @ w2^T + b2   [16384,384] K=1536
    gemm_mfma2_kernel<0, true, true>
        <<<dim3(M_ROWS / 128, 3), 256, 0, stream>>>(
            xzb, DFF, wh + OFF_W2, wl + OFF_W2, DFF, b2 + (size_t)l * D, x, x,
            D, DFF);
  }

  ln_kernel<<<M_ROWS / 4, 256, 0, stream>>>(x, lnfg, lnfb, u);
  // logits = u @ head_w^T + head_b   [16384,65] K=384
  gemm_kernel<64, 64, 16, 4, 4, 0, true, false>
      <<<dim3(M_ROWS / 64, 2), 256, 0, stream>>>(u, D, hw, D, hb, nullptr, out,
                                                 V, V, D);
  loss_rows_kernel<<<M_ROWS / 4, 256, 0, stream>>>(out, tgt, part);
  loss_final_kernel<<<1, 256, 0, stream>>>(part, out + (size_t)M_ROWS * V);
}

// Round 9
// 6952.987 us; speedup vs baseline: 2.9699x; 1.2472x over previous
//
#include <hip/hip_runtime.h>
#include <hip/hip_bf16.h>
#include <math.h>

#define V 65
#define D 384
#define NL 12
#define T 512
#define B 32
#define DI 768
#define DS 16
#define DC 4
#define DTR 24
#define DFF 1536
#define EPS 1e-5f
#define M_ROWS (B*T)   // 16384
#define NCHUNK 16
#define CLEN (T/NCHUNK)   // 32

typedef __bf16 bf16_t;
typedef bf16_t bf16x4_t __attribute__((ext_vector_type(4)));
typedef bf16_t bf16x8_t __attribute__((ext_vector_type(8)));
typedef float f32x4_t __attribute__((ext_vector_type(4)));

// swizzled element index in a [128][64] bf16 LDS tile: XOR 8-elem slot by row&7
#define SWZ64(row, k) (((row) << 6) + ((k) ^ (((row) & 7) << 3)))

// weight hi/lo buffer offsets (elements) within the rotating per-layer buffer
#define OFF_IN  0
#define OFF_DT  589824
#define OFF_OUT 608256
#define OFF_W1  903168
#define OFF_W2  1492992
#define WTOT    2082816

// ---------------- embedding ----------------
__global__ __launch_bounds__(256) void embed_kernel(
    const int* __restrict__ idx, const float* __restrict__ tok,
    const float* __restrict__ pos, float* __restrict__ x) {
  int i = blockIdx.x * 256 + threadIdx.x;
  int row = i / D, d = i - row * D;
  int t = row % T;
  x[i] = tok[idx[row] * D + d] + pos[t * D + d];
}

// ---------------- fp32 -> (hi,lo) bf16 split ----------------
__global__ __launch_bounds__(256) void cvt_hilo_kernel(
    const float* __restrict__ src, bf16_t* __restrict__ h,
    bf16_t* __restrict__ l, int n) {
  int i = (blockIdx.x * 256 + threadIdx.x) * 4;
  if (i >= n) return;
  float4 v = *(const float4*)(src + i);
  bf16x4_t vh, vl;
  vh[0] = (bf16_t)v.x; vl[0] = (bf16_t)(v.x - (float)vh[0]);
  vh[1] = (bf16_t)v.y; vl[1] = (bf16_t)(v.y - (float)vh[1]);
  vh[2] = (bf16_t)v.z; vl[2] = (bf16_t)(v.z - (float)vh[2]);
  vh[3] = (bf16_t)v.w; vl[3] = (bf16_t)(v.w - (float)vh[3]);
  *(bf16x4_t*)(h + i) = vh;
  *(bf16x4_t*)(l + i) = vl;
}

// ---------------- layernorm (1 wave per row of D=384) ----------------
__global__ __launch_bounds__(256) void ln_kernel(
    const float* __restrict__ in, const float* __restrict__ g,
    const float* __restrict__ b, float* __restrict__ out) {
  int wave = threadIdx.x >> 6;
  int lane = threadIdx.x & 63;
  int row = blockIdx.x * 4 + wave;
  const float* p = in + (size_t)row * D;
  float v[6];
  float s = 0.f, ss = 0.f;
#pragma unroll
  for (int i = 0; i < 6; i++) {
    v[i] = p[lane + i * 64];
    s += v[i];
    ss += v[i] * v[i];
  }
#pragma unroll
  for (int o = 1; o < 64; o <<= 1) {
    s += __shfl_xor(s, o, 64);
    ss += __shfl_xor(ss, o, 64);
  }
  float mu = s * (1.f / D);
  float var = ss * (1.f / D) - mu * mu;
  float rs = rsqrtf(var + EPS);
  float* q = out + (size_t)row * D;
#pragma unroll
  for (int i = 0; i < 6; i++) {
    int d = lane + i * 64;
    q[d] = (v[i] - mu) * rs * g[d] + b[d];
  }
}

// ---------------- bf16x3-split MFMA GEMM, B pre-split, 8 waves ----------------
// C[M,N] = A[M,K] @ Bw[N,K]^T.  A fp32 (split in-kernel); B given as hi/lo bf16.
// BM=BN=128, BK=64, 8 waves (512 thr), wave tile 64x32.
// ACT: 0 none, 1 relu, 2 softplus.
template <int ACT, bool BIAS, bool RES>
__global__ __launch_bounds__(512, 4) void gemm_mfma2_kernel(
    const float* __restrict__ A, int lda,
    const bf16_t* __restrict__ Bhg, const bf16_t* __restrict__ Blg, int ldb,
    const float* __restrict__ bias,
    const float* res,            // may alias C
    float* C, int ldc, int K) {
  __shared__ bf16_t Ah[128 * 64];
  __shared__ bf16_t Al[128 * 64];
  __shared__ bf16_t Bh[128 * 64];
  __shared__ bf16_t Bl[128 * 64];
  const int tid = threadIdx.x;
  const int m0 = blockIdx.x * 128, n0 = blockIdx.y * 128;
  const int lane = tid & 63, w = tid >> 6;          // w: 0..7
  const int wm = (w >> 2) * 64, wn = (w & 3) * 32;  // 2x4 wave grid
  const float* Abase = A + (size_t)m0 * lda;
  const bf16_t* Bhbase = Bhg + (size_t)n0 * ldb;
  const bf16_t* Blbase = Blg + (size_t)n0 * ldb;

  f32x4_t acc[4][2] = {};

  for (int k0 = 0; k0 < K; k0 += 64) {
    // ---- stage A tile fp32 -> (hi,lo) bf16 (2048 float4 over 512 thr) ----
#pragma unroll
    for (int i = 0; i < 4; i++) {
      int q = tid + (i << 9);
      int row = q >> 4, kc = (q & 15) << 2;
      float4 va = make_float4(0.f, 0.f, 0.f, 0.f);
      if (k0 + kc < K)
        va = *(const float4*)(Abase + (size_t)row * lda + k0 + kc);
      bf16x4_t ah, al;
      float f;
      ah[0] = (bf16_t)va.x; f = (float)ah[0]; al[0] = (bf16_t)(va.x - f);
      ah[1] = (bf16_t)va.y; f = (float)ah[1]; al[1] = (bf16_t)(va.y - f);
      ah[2] = (bf16_t)va.z; f = (float)ah[2]; al[2] = (bf16_t)(va.z - f);
      ah[3] = (bf16_t)va.w; f = (float)ah[3]; al[3] = (bf16_t)(va.w - f);
      int o = SWZ64(row, kc);
      *(bf16x4_t*)&Ah[o] = ah;
      *(bf16x4_t*)&Al[o] = al;
    }
    // ---- stage B tile: pure bf16x8 copy (1024 slots over 512 thr) ----
#pragma unroll
    for (int i = 0; i < 2; i++) {
      int q = tid + (i << 9);            // 0..1023 over 128 rows x 8 col8
      int row = q >> 3, c8 = (q & 7) << 3;
      bf16x8_t vh = {}, vl = {};
      if (k0 + c8 < K) {
        vh = *(const bf16x8_t*)(Bhbase + (size_t)row * ldb + k0 + c8);
        vl = *(const bf16x8_t*)(Blbase + (size_t)row * ldb + k0 + c8);
      }
      int o = SWZ64(row, c8);
      *(bf16x8_t*)&Bh[o] = vh;
      *(bf16x8_t*)&Bl[o] = vl;
    }
    __syncthreads();
    // ---- MFMA over the K-tile (2 k-slices of 32) ----
#pragma unroll
    for (int ks = 0; ks < 2; ks++) {
      int kk = ks * 32 + ((lane >> 4) << 3);
      bf16x8_t a_h[4], a_l[4], b_h[2], b_l[2];
#pragma unroll
      for (int f = 0; f < 4; f++) {
        int ra = wm + f * 16 + (lane & 15);
        a_h[f] = *(bf16x8_t*)&Ah[SWZ64(ra, kk)];
        a_l[f] = *(bf16x8_t*)&Al[SWZ64(ra, kk)];
      }
#pragma unroll
      for (int g = 0; g < 2; g++) {
        int rb = wn + g * 16 + (lane & 15);
        b_h[g] = *(bf16x8_t*)&Bh[SWZ64(rb, kk)];
        b_l[g] = *(bf16x8_t*)&Bl[SWZ64(rb, kk)];
      }
#pragma unroll
      for (int mf = 0; mf < 4; mf++)
#pragma unroll
        for (int nf = 0; nf < 2; nf++) {
          acc[mf][nf] = __builtin_amdgcn_mfma_f32_16x16x32_bf16(
              a_h[mf], b_h[nf], acc[mf][nf], 0, 0, 0);
          acc[mf][nf] = __builtin_amdgcn_mfma_f32_16x16x32_bf16(
              a_l[mf], b_h[nf], acc[mf][nf], 0, 0, 0);
          acc[mf][nf] = __builtin_amdgcn_mfma_f32_16x16x32_bf16(
              a_h[mf], b_l[nf], acc[mf][nf], 0, 0, 0);
        }
    }
    __syncthreads();
  }

  // ---- epilogue: C/D layout row=(lane>>4)*4+j, col=lane&15 ----
  const int rbase = m0 + wm + ((lane >> 4) << 2);
  const int cbase = n0 + wn + (lane & 15);
#pragma unroll
  for (int mf = 0; mf < 4; mf++)
#pragma unroll
    for (int nf = 0; nf < 2; nf++) {
      int n = cbase + nf * 16;
      float bv = BIAS ? bias[n] : 0.f;
#pragma unroll
      for (int j = 0; j < 4; j++) {
        int m = rbase + mf * 16 + j;
        float v = acc[mf][nf][j];
        if (BIAS) v += bv;
        if (ACT == 1) v = fmaxf(v, 0.f);
        if (ACT == 2) v = fmaxf(v, 0.f) + log1pf(expf(-fabsf(v)));
        if (RES) v += res[(size_t)m * ldc + n];
        C[(size_t)m * ldc + n] = v;
      }
    }
}

// ---------------- small fp32 VALU GEMM (x_proj N=56, head N=65) ----------------
template <int BM, int BN, int BK, int TM, int TN, int ACT, bool BIAS, bool RES>
__global__ __launch_bounds__(256) void gemm_kernel(
    const float* __restrict__ A, int lda,
    const float* __restrict__ Bw, int ldb,
    const float* __restrict__ bias,
    const float* res, float* C, int ldc,
    int N, int K) {
  __shared__ float As[BK][BM];
  __shared__ float Bs[BK][BN];
  const int tid = threadIdx.x;
  const int m0 = blockIdx.x * BM;
  const int n0 = blockIdx.y * BN;
  constexpr int MT = BM / TM;
  const int tm0 = (tid % MT) * TM;
  const int tn0 = (tid / MT) * TN;
  constexpr int K4 = BK / 4;
  constexpr int A_LOADS = BM * BK / 4 / 256;
  constexpr int B_LOADS = BN * BK / 4 / 256;

  float acc[TM][TN] = {};

  for (int k0 = 0; k0 < K; k0 += BK) {
#pragma unroll
    for (int i = 0; i < A_LOADS; i++) {
      int id = tid + i * 256;
      int row = id / K4, kc = (id % K4) * 4;
      float4 v = make_float4(0.f, 0.f, 0.f, 0.f);
      if (k0 + kc < K)
        v = *(const float4*)(A + (size_t)(m0 + row) * lda + k0 + kc);
      As[kc + 0][row] = v.x; As[kc + 1][row] = v.y;
      As[kc + 2][row] = v.z; As[kc + 3][row] = v.w;
    }
#pragma unroll
    for (int i = 0; i < B_LOADS; i++) {
      int id = tid + i * 256;
      int row = id / K4, kc = (id % K4) * 4;
      float4 v = make_float4(0.f, 0.f, 0.f, 0.f);
      if ((n0 + row) < N && (k0 + kc) < K)
        v = *(const float4*)(Bw + (size_t)(n0 + row) * ldb + k0 + kc);
      Bs[kc + 0][row] = v.x; Bs[kc + 1][row] = v.y;
      Bs[kc + 2][row] = v.z; Bs[kc + 3][row] = v.w;
    }
    __syncthreads();
#pragma unroll
    for (int k = 0; k < BK; k++) {
      float a[TM], bb[TN];
#pragma unroll
      for (int i = 0; i < TM; i++) a[i] = As[k][tm0 + i];
#pragma unroll
      for (int j = 0; j < TN; j++) bb[j] = Bs[k][tn0 + j];
#pragma unroll
      for (int i = 0; i < TM; i++)
#pragma unroll
        for (int j = 0; j < TN; j++) acc[i][j] += a[i] * bb[j];
    }
    __syncthreads();
  }

#pragma unroll
  for (int i = 0; i < TM; i++) {
    int m = m0 + tm0 + i;
#pragma unroll
    for (int j = 0; j < TN; j++) {
      int n = n0 + tn0 + j;
      if (n < N) {
        float v = acc[i][j];
        if (BIAS) v += bias[n];
        if (ACT == 1) v = fmaxf(v, 0.f);
        if (ACT == 2) v = fmaxf(v, 0.f) + log1pf(expf(-fabsf(v)));
        if (RES) v += res[(size_t)m * ldc + n];
        C[(size_t)m * ldc + n] = v;
      }
    }
  }
}

// ---------------- causal depthwise conv (DC=4) + SiLU; also silu(z) in-place ----
__global__ __launch_bounds__(256) void conv_silu_kernel(
    float* xz, const float* __restrict__ cw,
    const float* __restrict__ cb, float* __restrict__ xc) {
  int i = blockIdx.x * 256 + threadIdx.x;   // over M_ROWS*DI
  int row = i / DI, d = i - row * DI;
  int t = row % T;
  float acc = cb[d];
#pragma unroll
  for (int k = 0; k < DC; k++) {
    int tt = t + k - (DC - 1);
    if (tt >= 0)
      acc += xz[(size_t)(row + k - (DC - 1)) * (2 * DI) + d] * cw[d * DC + k];
  }
  float sg = 1.f / (1.f + __expf(-acc));
  xc[i] = acc * sg;
  size_t zi = (size_t)row * (2 * DI) + DI + d;
  float zv = xz[zi];
  xz[zi] = zv / (1.f + __expf(-zv));
}

// ---------------- chunked selective scan (no cross-lane ops) ----------------
__global__ __launch_bounds__(256) void scan_chunked_kernel(
    const float* __restrict__ xc,   // [M_ROWS, DI]
    const float* __restrict__ xdbl, // [M_ROWS, 56]
    const float* dt,                // [M_ROWS, DI]  (aliases y)
    const float* __restrict__ xz,   // [M_ROWS, 2*DI]; z-half holds silu(z)
    const float* __restrict__ A_log,// [DI, DS]
    const float* __restrict__ Dskip,// [DI]
    float* y) {                     // [M_ROWS, DI]
  __shared__ float hfin[NCHUNK][16][DS];   // 16 KB (becomes h0 after combine)
  __shared__ float sdt[NCHUNK][16];        // 1 KB
  const int tid = threadIdx.x;
  const int dch = tid & 15, ch = tid >> 4;
  const int d0 = (blockIdx.x % (DI / 16)) * 16;
  const int b = blockIdx.x / (DI / 16);
  const int d = d0 + dch;
  float A[DS];
#pragma unroll
  for (int s = 0; s < DS; s++) A[s] = -__expf(A_log[d * DS + s]);
  const size_t rbase = (size_t)b * T + (size_t)ch * CLEN;
  const float* pdt = dt + rbase * DI + d;
  const float* pxc = xc + rbase * DI + d;
  const float* pbc = xdbl + rbase * 56;

  // ---- pass 1 ----
  float h[DS];
#pragma unroll
  for (int s = 0; s < DS; s++) h[s] = 0.f;
  float sd = 0.f;
  for (int t = 0; t < CLEN; t++) {
    float dtv = pdt[(size_t)t * DI];
    float xv = pxc[(size_t)t * DI];
    float bb[DS];
#pragma unroll
    for (int j = 0; j < 4; j++)
      *(float4*)&bb[4 * j] = *(const float4*)(pbc + (size_t)t * 56 + 24 + 4 * j);
    float dx = dtv * xv;
    sd += dtv;
#pragma unroll
    for (int s = 0; s < DS; s++)
      h[s] = fmaf(__expf(dtv * A[s]), h[s], dx * bb[s]);
  }
  sdt[ch][dch] = sd;
#pragma unroll
  for (int s = 0; s < DS; s++) hfin[ch][dch][s] = h[s];
  __syncthreads();

  // ---- combine: thread = (dc, sc) ----
  {
    const int dc = tid >> 4, sc = tid & 15;
    float As = -__expf(A_log[(d0 + dc) * DS + sc]);
    float h0 = 0.f;
#pragma unroll
    for (int c = 0; c < NCHUNK; c++) {
      float hf = hfin[c][dc][sc];
      float P = __expf(As * sdt[c][dc]);
      hfin[c][dc][sc] = h0;            // incoming state for chunk c
      h0 = fmaf(P, h0, hf);
    }
  }
  __syncthreads();

  // ---- pass 2 ----
#pragma unroll
  for (int s = 0; s < DS; s++) h[s] = hfin[ch][dch][s];
  const float Dp = Dskip[d];
  const float* pz = xz + rbase * (2 * DI) + DI + d;
  float* py = y + rbase * DI + d;
  for (int t = 0; t < CLEN; t++) {
    float dtv = pdt[(size_t)t * DI];
    float xv = pxc[(size_t)t * DI];
    float bb[DS], cc[DS];
#pragma unroll
    for (int j = 0; j < 4; j++) {
      *(float4*)&bb[4 * j] = *(const float4*)(pbc + (size_t)t * 56 + 24 + 4 * j);
      *(float4*)&cc[4 * j] = *(const float4*)(pbc + (size_t)t * 56 + 40 + 4 * j);
    }
    float dx = dtv * xv;
    float acc = 0.f;
#pragma unroll
    for (int s = 0; s < DS; s++) {
      h[s] = fmaf(__expf(dtv * A[s]), h[s], dx * bb[s]);
      acc = fmaf(h[s], cc[s], acc);
    }
    float yv = (acc + xv * Dp) * pz[(size_t)t * 2 * DI];
    py[(size_t)t * DI] = yv;
  }
}

// ---------------- loss ----------------
__global__ __launch_bounds__(256) void loss_rows_kernel(
    const float* __restrict__ logits, const int* __restrict__ tgt,
    float* __restrict__ partials) {
  int wave = threadIdx.x >> 6, lane = threadIdx.x & 63;
  int row = blockIdx.x * 4 + wave;
  const float* p = logits + (size_t)row * V;
  float v0 = (lane < V) ? p[lane] : -INFINITY;
  float v1 = (lane + 64 < V) ? p[lane + 64] : -INFINITY;
  float mx = fmaxf(v0, v1);
#pragma unroll
  for (int o = 1; o < 64; o <<= 1) mx = fmaxf(mx, __shfl_xor(mx, o, 64));
  float e = ((lane < V) ? expf(v0 - mx) : 0.f) +
            ((lane + 64 < V) ? expf(v1 - mx) : 0.f);
#pragma unroll
  for (int o = 1; o < 64; o <<= 1) e += __shfl_xor(e, o, 64);
  float lse = mx + logf(e);
  __shared__ float sm[4];
  if (lane == 0) sm[wave] = lse - p[tgt[row]];
  __syncthreads();
  if (threadIdx.x == 0)
    partials[blockIdx.x] = sm[0] + sm[1] + sm[2] + sm[3];
}

__global__ __launch_bounds__(256) void loss_final_kernel(
    const float* __restrict__ partials, float* __restrict__ out) {
  double s = 0.0;
  for (int i = threadIdx.x; i < 4096; i += 256) s += (double)partials[i];
  __shared__ double sm[256];
  sm[threadIdx.x] = s;
  __syncthreads();
  for (int st = 128; st > 0; st >>= 1) {
    if (threadIdx.x < st) sm[threadIdx.x] += sm[threadIdx.x + st];
    __syncthreads();
  }
  if (threadIdx.x == 0) out[0] = (float)(sm[0] / (double)(B * T));
}

// ---------------- host launch ----------------
extern "C" void kernel_launch(void* const* d_in, const int* in_sizes, int n_in,
                              void* d_out, int out_size, void* d_ws,
                              size_t ws_size, hipStream_t stream) {
  const int* idx = (const int*)d_in[0];
  const int* tgt = (const int*)d_in[1];
  const float* tok = (const float*)d_in[2];
  const float* pos = (const float*)d_in[3];
  const float* ln1g = (const float*)d_in[4];
  const float* ln1b = (const float*)d_in[5];
  const float* inw = (const float*)d_in[6];
  const float* convw = (const float*)d_in[7];
  const float* convb = (const float*)d_in[8];
  const float* xpw = (const float*)d_in[9];
  const float* dtpw = (const float*)d_in[10];
  const float* dtpb = (const float*)d_in[11];
  const float* alog = (const float*)d_in[12];
  const float* dskip = (const float*)d_in[13];
  const float* outw = (const float*)d_in[14];
  const float* ln2g = (const float*)d_in[15];
  const float* ln2b = (const float*)d_in[16];
  const float* w1 = (const float*)d_in[17];
  const float* b1 = (const float*)d_in[18];
  const float* w2 = (const float*)d_in[19];
  const float* b2 = (const float*)d_in[20];
  const float* lnfg = (const float*)d_in[21];
  const float* lnfb = (const float*)d_in[22];
  const float* hw = (const float*)d_in[23];
  const float* hb = (const float*)d_in[24];
  float* out = (float*)d_out;

  char* ws = (char*)d_ws;
  size_t o = 0;
  float* x = (float*)(ws + o);   o += (size_t)M_ROWS * D * 4;
  float* u = (float*)(ws + o);   o += (size_t)M_ROWS * D * 4;
  float* xzb = (float*)(ws + o); o += (size_t)M_ROWS * 2 * DI * 4;
  float* xcb = (float*)(ws + o); o += (size_t)M_ROWS * DI * 4;
  float* xdb = (float*)(ws + o); o += (size_t)M_ROWS * 56 * 4;
  float* dtb = (float*)(ws + o); o += (size_t)M_ROWS * DI * 4;
  float* part = (float*)(ws + o); o += 4096 * 4;
  bf16_t* wh = (bf16_t*)(ws + o); o += (size_t)WTOT * 2;
  bf16_t* wl = (bf16_t*)(ws + o); o += (size_t)WTOT * 2;
  float* yb = dtb;  // alias: scan pass2 reads dt[row,d] before writing y[row,d]

  embed_kernel<<<M_ROWS * D / 256, 256, 0, stream>>>(idx, tok, pos, x);

  for (int l = 0; l < NL; l++) {
    // pre-split this layer's weights into (hi,lo) bf16
    cvt_hilo_kernel<<<576, 256, 0, stream>>>(inw + (size_t)l * 2 * DI * D,
                                             wh + OFF_IN, wl + OFF_IN, 589824);
    cvt_hilo_kernel<<<18, 256, 0, stream>>>(dtpw + (size_t)l * DI * DTR,
                                            wh + OFF_DT, wl + OFF_DT, 18432);
    cvt_hilo_kernel<<<288, 256, 0, stream>>>(outw + (size_t)l * D * DI,
                                             wh + OFF_OUT, wl + OFF_OUT, 294912);
    cvt_hilo_kernel<<<576, 256, 0, stream>>>(w1 + (size_t)l * DFF * D,
                                             wh + OFF_W1, wl + OFF_W1, 589824);
    cvt_hilo_kernel<<<576, 256, 0, stream>>>(w2 + (size_t)l * D * DFF,
                                             wh + OFF_W2, wl + OFF_W2, 589824);

    ln_kernel<<<M_ROWS / 4, 256, 0, stream>>>(x, ln1g + l * D, ln1b + l * D, u);
    // xz = u @ in_w^T   [16384,1536] K=384
    gemm_mfma2_kernel<0, false, false>
        <<<dim3(M_ROWS / 128, 12), 512, 0, stream>>>(
            u, D, wh + OFF_IN, wl + OFF_IN, D, nullptr, nullptr, xzb, 2 * DI, D);
    conv_silu_kernel<<<M_ROWS * DI / 256, 256, 0, stream>>>(
        xzb, convw + (size_t)l * DI * DC, convb + (size_t)l * DI, xcb);
    // x_dbl = xc @ xp_w^T   [16384,56] K=768  (small-N: VALU gemm)
    gemm_kernel<64, 64, 16, 4, 4, 0, false, false>
        <<<dim3(M_ROWS / 64, 1), 256, 0, stream>>>(
            xcb, DI, xpw + (size_t)l * (DTR + 2 * DS) * DI, DI, nullptr,
            nullptr, xdb, 56, 56, DI);
    // dt = softplus(x_dbl[:, :24] @ dtp_w^T + b)   [16384,768] K=24
    gemm_mfma2_kernel<2, true, false>
        <<<dim3(M_ROWS / 128, 6), 512, 0, stream>>>(
            xdb, 56, wh + OFF_DT, wl + OFF_DT, DTR, dtpb + (size_t)l * DI,
            nullptr, dtb, DI, DTR);
    scan_chunked_kernel<<<B * (DI / 16), 256, 0, stream>>>(
        xcb, xdb, dtb, xzb, alog + (size_t)l * DI * DS, dskip + (size_t)l * DI,
        yb);
    // x += y @ out_w^T   [16384,384] K=768
    gemm_mfma2_kernel<0, false, true>
        <<<dim3(M_ROWS / 128, 3), 512, 0, stream>>>(
            yb, DI, wh + OFF_OUT, wl + OFF_OUT, DI, nullptr, x, x, D, DI);
    ln_kernel<<<M_ROWS / 4, 256, 0, stream>>>(x, ln2g + l * D, ln2b + l * D, u);
    // h = relu(u @ w1^T + b1)   [16384,1536] K=384
    gemm_mfma2_kernel<1, true, false>
        <<<dim3(M_ROWS / 128, 12), 512, 0, stream>>>(
            u, D, wh + OFF_W1, wl + OFF_W1, D, b1 + (size_t)l * DFF, nullptr,
            xzb, DFF, D);
    // x += h @ w2^T + b2   [16384,384] K=1536
    gemm_mfma2_kernel<0, true, true>
        <<<dim3(M_ROWS / 128, 3), 512, 0, stream>>>(
            xzb, DFF, wh + OFF_W2, wl + OFF_W2, DFF, b2 + (size_t)l * D, x, x,
            D, DFF);
  }

  ln_kernel<<<M_ROWS / 4, 256, 0, stream>>>(x, lnfg, lnfb, u);
  // logits = u @ head_w^T + head_b   [16384,65] K=384
  gemm_kernel<64, 64, 16, 4, 4, 0, true, false>
      <<<dim3(M_ROWS / 64, 2), 256, 0, stream>>>(u, D, hw, D, hb, nullptr, out,
                                                 V, V, D);
  loss_rows_kernel<<<M_ROWS / 4, 256, 0, stream>>>(out, tgt, part);
  loss_final_kernel<<<1, 256, 0, stream>>>(part, out + (size_t)M_ROWS * V);
}